// Round 2
// baseline (464.570 us; speedup 1.0000x reference)
//
#include <hip/hip_runtime.h>

// LengthRegulator: B=32, T=1024, D=384, MAXLEN=8192 (fixed by harness).
// Output-centric formulation: each output row (b,p) gathers x[b, ub(cum[b],p)]
// if p < total[b], else zero. One dense pass over d_out (the 402 MB write IS
// the roofline term); cum[b] staged in LDS, 32 binary searches per block.

#define B_   32
#define T_   1024
#define D_   384
#define ML_  8192
#define D4_  (D_ / 4)    // 96 float4 per row
#define RPB  32          // output rows per block (48 KB of writes)

// --- Kernel 1: per-batch inclusive scan of clamped durations -------------
// Wave-shuffle scan: 16 waves x 64-lane shfl scan + 16-partial scan, 2 barriers.
__global__ __launch_bounds__(T_) void lr_scan(const int* __restrict__ dur,
                                              int* __restrict__ cum,
                                              float* __restrict__ total_out) {
    const int b = blockIdx.x;
    const int t = threadIdx.x;
    const int lane = t & 63;
    const int wave = t >> 6;

    int v = dur[b * T_ + t];
    v = v > 0 ? v : 0;

    // inclusive scan within the 64-lane wave
    for (int off = 1; off < 64; off <<= 1) {
        int n = __shfl_up(v, off, 64);
        if (lane >= off) v += n;
    }

    __shared__ int wsum[16];
    if (lane == 63) wsum[wave] = v;
    __syncthreads();

    if (wave == 0 && lane < 16) {
        int w = wsum[lane];
        for (int off = 1; off < 16; off <<= 1) {
            int n = __shfl_up(w, off, 64);   // sources are lanes 0..15 (active)
            if (lane >= off) w += n;
        }
        wsum[lane] = w;
    }
    __syncthreads();

    int c = v + (wave > 0 ? wsum[wave - 1] : 0);
    cum[b * T_ + t] = c;
    if (t == T_ - 1) {
        // d_out is read back as one flat fp32 buffer -> total stored as float
        total_out[b] = (float)c;   // <= 15360, exact in fp32
    }
}

// --- Kernel 2: dense gather-copy — one block per 32 output rows ----------
__global__ __launch_bounds__(256) void lr_copy(const float4* __restrict__ x,
                                               const int* __restrict__ cum,
                                               float4* __restrict__ out) {
    __shared__ int scum[T_];
    __shared__ int ridx[RPB];

    const int b  = blockIdx.y;
    const int p0 = blockIdx.x * RPB;
    const int t  = threadIdx.x;

    // stage cum[b][0..1023] (4 KB) into LDS: 256 threads x int4
    ((int4*)scum)[t] = ((const int4*)(cum + b * T_))[t];
    __syncthreads();

    const int total = scum[T_ - 1];

    // 32 binary searches (upper_bound) by the first 32 lanes
    if (t < RPB) {
        const int p = p0 + t;
        int lo = 0, hi = T_;
        while (lo < hi) {
            int mid = (lo + hi) >> 1;
            if (scum[mid] <= p) lo = mid + 1; else hi = mid;
        }
        ridx[t] = lo < (T_ - 1) ? lo : (T_ - 1);
    }
    __syncthreads();

    // dense copy: 32 rows x 96 float4 = 3072 elems, 256 threads -> 12 iters.
    // Store address == flat element index -> perfectly linear streaming writes.
    const float4 z = make_float4(0.f, 0.f, 0.f, 0.f);
    const float4* xb = x + (size_t)b * T_ * D4_;
    float4* ob = out + ((size_t)b * ML_ + p0) * D4_;

    #pragma unroll
    for (int k = 0; k < (RPB * D4_) / 256; ++k) {
        const int e = t + k * 256;
        const int r = e / D4_;          // constant div by 96
        const int c = e - r * D4_;
        const int p = p0 + r;
        float4 v = (p < total) ? xb[(size_t)ridx[r] * D4_ + c] : z;
        ob[e] = v;
    }
}

extern "C" void kernel_launch(void* const* d_in, const int* in_sizes, int n_in,
                              void* d_out, int out_size, void* d_ws, size_t ws_size,
                              hipStream_t stream) {
    const float* x   = (const float*)d_in[0];   // (B, T, D) fp32
    const int*   dur = (const int*)d_in[1];     // (B, T) int32
    // d_in[2] = max_len scalar (always 8192 here)

    float* out       = (float*)d_out;                   // (B, ML, D) fp32
    float* total_out = out + (size_t)B_ * ML_ * D_;     // (B,) as fp32
    int*   cum       = (int*)d_ws;                      // (B, T) scratch

    lr_scan<<<B_, T_, 0, stream>>>(dur, cum, total_out);
    lr_copy<<<dim3(ML_ / RPB, B_), 256, 0, stream>>>((const float4*)x, cum,
                                                     (float4*)out);
}

// Round 3
// 441.104 us; speedup vs baseline: 1.0532x; 1.0532x over previous
//
#include <hip/hip_runtime.h>

// LengthRegulator: B=32, T=1024, D=384, MAXLEN=8192 (fixed by harness).
// Frame-centric expand: frame t owns output rows [cum[t-1], cum[t]) — an exact
// partition of [0, total). Each block handles 8 frames with 768 threads; every
// lane holds one float4 of its frame's row in a register and stores it dur
// times (inner loop = store + addr-increment, fill-kernel shape). Tail
// zero-fill [total, ML) folded in via 32 extra fill-role blocks per batch.

#define B_    32
#define T_    1024
#define D_    384
#define ML_   8192
#define D4_   (D_ / 4)    // 96 float4 per row
#define FPB   8           // frames per block
#define NTHR  (FPB * D4_) // 768 threads = 12 waves
#define NFILL 32          // fill-role blocks per batch

// --- Kernel 1: per-batch inclusive scan of clamped durations -------------
__global__ __launch_bounds__(T_) void lr_scan(const int* __restrict__ dur,
                                              int* __restrict__ cum,
                                              float* __restrict__ total_out) {
    const int b = blockIdx.x;
    const int t = threadIdx.x;
    const int lane = t & 63;
    const int wave = t >> 6;

    int v = dur[b * T_ + t];
    v = v > 0 ? v : 0;

    for (int off = 1; off < 64; off <<= 1) {
        int n = __shfl_up(v, off, 64);
        if (lane >= off) v += n;
    }

    __shared__ int wsum[16];
    if (lane == 63) wsum[wave] = v;
    __syncthreads();

    if (wave == 0 && lane < 16) {
        int w = wsum[lane];
        for (int off = 1; off < 16; off <<= 1) {
            int n = __shfl_up(w, off, 64);
            if (lane >= off) w += n;
        }
        wsum[lane] = w;
    }
    __syncthreads();

    int c = v + (wave > 0 ? wsum[wave - 1] : 0);
    cum[b * T_ + t] = c;
    if (t == T_ - 1) {
        total_out[b] = (float)c;   // total <= 15360, exact in fp32
    }
}

// --- Kernel 2: expand + tail-fill ----------------------------------------
// grid = (T_/FPB + NFILL, B_). blockIdx.x < 128: expand role; else fill role.
__global__ __launch_bounds__(NTHR) void lr_expand2(const float4* __restrict__ x,
                                                   const int* __restrict__ cum,
                                                   float4* __restrict__ out) {
    const int b  = blockIdx.y;
    const int bi = blockIdx.x;
    const int t  = threadIdx.x;
    const int* cb = cum + b * T_;

    if (bi < T_ / FPB) {
        // ---- expand role: frames [f0, f0+8) ----
        const int f0 = bi * FPB;
        __shared__ int sc[FPB + 1];          // cum[f0-1 .. f0+7]
        if (t <= FPB) {
            int i = f0 - 1 + t;
            sc[t] = (i >= 0) ? cb[i] : 0;
        }
        __syncthreads();

        const int fl = t / D4_;              // frame within block (0..7)
        const int c  = t - fl * D4_;         // column float4 (0..95)

        int start = sc[fl];
        int end   = sc[fl + 1];
        if (end > ML_) end = ML_;            // total may exceed MAXLEN
        if (start >= end) return;

        const float4 v = x[((size_t)b * T_ + f0 + fl) * D4_ + c];
        float4* o = out + ((size_t)b * ML_ + start) * D4_ + c;
        for (int p = start; p < end; ++p) {
            *o = v;
            o += D4_;
        }
    } else {
        // ---- fill role: zero rows [min(total,ML), ML) ----
        const int fb = bi - T_ / FPB;        // 0..NFILL-1
        int total = cb[T_ - 1];
        const int tr = total < ML_ ? total : ML_;
        const int n  = (ML_ - tr) * D4_;
        float4* o = out + ((size_t)b * ML_ + tr) * D4_;
        const float4 z = make_float4(0.f, 0.f, 0.f, 0.f);
        const int stride = NFILL * NTHR;
        for (int i = fb * NTHR + t; i < n; i += stride)
            o[i] = z;
    }
}

extern "C" void kernel_launch(void* const* d_in, const int* in_sizes, int n_in,
                              void* d_out, int out_size, void* d_ws, size_t ws_size,
                              hipStream_t stream) {
    const float* x   = (const float*)d_in[0];   // (B, T, D) fp32
    const int*   dur = (const int*)d_in[1];     // (B, T) int32
    // d_in[2] = max_len scalar (always 8192 here)

    float* out       = (float*)d_out;                   // (B, ML, D) fp32
    float* total_out = out + (size_t)B_ * ML_ * D_;     // (B,) as fp32
    int*   cum       = (int*)d_ws;                      // (B, T) scratch

    lr_scan<<<B_, T_, 0, stream>>>(dur, cum, total_out);
    lr_expand2<<<dim3(T_ / FPB + NFILL, B_), NTHR, 0, stream>>>(
        (const float4*)x, cum, (float4*)out);
}

// Round 4
// 436.178 us; speedup vs baseline: 1.0651x; 1.0113x over previous
//
#include <hip/hip_runtime.h>

// LengthRegulator: B=32, T=1024, D=384, MAXLEN=8192 (fixed by harness).
// Frame-centric expand: frame t owns output rows [cum[t-1], cum[t]).
// R3 post-mortem: 768-thread blocks -> only 2 blocks/CU resident -> block
// startup (x-row load latency) bubbles serialize ~20 block generations/CU.
// R4: 192-thread blocks (2 frames x 96 lanes, exactly 3 waves) -> 10
// blocks/CU -> startup latency overlapped across generations.

#define B_    32
#define T_    1024
#define D_    384
#define ML_   8192
#define D4_   (D_ / 4)     // 96 float4 per row
#define FPB   2            // frames per block
#define NTHR  (FPB * D4_)  // 192 threads = exactly 3 waves
#define NEXP  (T_ / FPB)   // 512 expand-role blocks per batch
#define NFILL 32           // fill-role blocks per batch

// --- Kernel 1: per-batch inclusive scan of clamped durations -------------
__global__ __launch_bounds__(T_) void lr_scan(const int* __restrict__ dur,
                                              int* __restrict__ cum,
                                              float* __restrict__ total_out) {
    const int b = blockIdx.x;
    const int t = threadIdx.x;
    const int lane = t & 63;
    const int wave = t >> 6;

    int v = dur[b * T_ + t];
    v = v > 0 ? v : 0;

    for (int off = 1; off < 64; off <<= 1) {
        int n = __shfl_up(v, off, 64);
        if (lane >= off) v += n;
    }

    __shared__ int wsum[16];
    if (lane == 63) wsum[wave] = v;
    __syncthreads();

    if (wave == 0 && lane < 16) {
        int w = wsum[lane];
        for (int off = 1; off < 16; off <<= 1) {
            int n = __shfl_up(w, off, 64);
            if (lane >= off) w += n;
        }
        wsum[lane] = w;
    }
    __syncthreads();

    int c = v + (wave > 0 ? wsum[wave - 1] : 0);
    cum[b * T_ + t] = c;
    if (t == T_ - 1) {
        total_out[b] = (float)c;   // total <= 15360, exact in fp32
    }
}

// --- Kernel 2: expand + tail-fill ----------------------------------------
// grid = (NEXP + NFILL, B_). bi < NEXP: expand role; else fill role.
__global__ __launch_bounds__(NTHR) void lr_expand3(const float4* __restrict__ x,
                                                   const int* __restrict__ cum,
                                                   float4* __restrict__ out) {
    const int b  = blockIdx.y;
    const int bi = blockIdx.x;
    const int t  = threadIdx.x;
    const int* cb = cum + b * T_;

    if (bi < NEXP) {
        // ---- expand role: frames [f0, f0+2) ----
        const int f0 = bi * FPB;
        __shared__ int sc[FPB + 1];          // cum[f0-1 .. f0+1]
        if (t <= FPB) {
            const int i = f0 - 1 + t;
            sc[t] = (i >= 0) ? cb[i] : 0;
        }
        __syncthreads();

        const int fl = (t >= D4_) ? 1 : 0;   // frame within block
        const int c  = t - fl * D4_;         // column float4 (0..95)

        int start = sc[fl];
        int end   = sc[fl + 1];
        if (end > ML_) end = ML_;            // total may exceed MAXLEN
        if (start >= end) return;

        const float4 v = x[((size_t)b * T_ + f0 + fl) * D4_ + c];
        float4* o = out + ((size_t)b * ML_ + start) * D4_ + c;
        for (int p = start; p < end; ++p) {
            *o = v;
            o += D4_;
        }
    } else {
        // ---- fill role: zero rows [min(total,ML), ML) ----
        const int fb = bi - NEXP;            // 0..NFILL-1
        const int total = cb[T_ - 1];
        const int tr = total < ML_ ? total : ML_;
        const int n  = (ML_ - tr) * D4_;
        float4* o = out + ((size_t)b * ML_ + tr) * D4_;
        const float4 z = make_float4(0.f, 0.f, 0.f, 0.f);
        const int stride = NFILL * NTHR;
        for (int i = fb * NTHR + t; i < n; i += stride)
            o[i] = z;
    }
}

extern "C" void kernel_launch(void* const* d_in, const int* in_sizes, int n_in,
                              void* d_out, int out_size, void* d_ws, size_t ws_size,
                              hipStream_t stream) {
    const float* x   = (const float*)d_in[0];   // (B, T, D) fp32
    const int*   dur = (const int*)d_in[1];     // (B, T) int32
    // d_in[2] = max_len scalar (always 8192 here)

    float* out       = (float*)d_out;                   // (B, ML, D) fp32
    float* total_out = out + (size_t)B_ * ML_ * D_;     // (B,) as fp32
    int*   cum       = (int*)d_ws;                      // (B, T) scratch

    lr_scan<<<B_, T_, 0, stream>>>(dur, cum, total_out);
    lr_expand3<<<dim3(NEXP + NFILL, B_), NTHR, 0, stream>>>(
        (const float4*)x, cum, (float4*)out);
}

// Round 5
// 434.163 us; speedup vs baseline: 1.0700x; 1.0046x over previous
//
#include <hip/hip_runtime.h>

// LengthRegulator: B=32, T=1024, D=384, MAXLEN=8192 (fixed by harness).
// Frame-centric expand, v4: one frame per 192-thread block (3 waves, 100%
// lanes). A frame's dur copies are CONSECUTIVE IDENTICAL rows, so lanes cover
// a 2-row window (192 float4 = 3 KB): every wave store is a single contiguous
// 1 KB transaction (no row-straddle splits). cum read via 2 wave-uniform
// scalar loads — no LDS, no barrier. Tail zero-fill via 32 contiguous-slice
// fill blocks per batch, fused in the same launch.

#define B_    32
#define T_    1024
#define D_    384
#define ML_   8192
#define D4_   (D_ / 4)     // 96 float4 per row
#define NTHR  192          // 2 rows per window, exactly 3 waves
#define NFILL 32           // fill-role blocks per batch

// --- Kernel 1: per-batch inclusive scan of clamped durations -------------
__global__ __launch_bounds__(T_) void lr_scan(const int* __restrict__ dur,
                                              int* __restrict__ cum,
                                              float* __restrict__ total_out) {
    const int b = blockIdx.x;
    const int t = threadIdx.x;
    const int lane = t & 63;
    const int wave = t >> 6;

    int v = dur[b * T_ + t];
    v = v > 0 ? v : 0;

    for (int off = 1; off < 64; off <<= 1) {
        int n = __shfl_up(v, off, 64);
        if (lane >= off) v += n;
    }

    __shared__ int wsum[16];
    if (lane == 63) wsum[wave] = v;
    __syncthreads();

    if (wave == 0 && lane < 16) {
        int w = wsum[lane];
        for (int off = 1; off < 16; off <<= 1) {
            int n = __shfl_up(w, off, 64);
            if (lane >= off) w += n;
        }
        wsum[lane] = w;
    }
    __syncthreads();

    int c = v + (wave > 0 ? wsum[wave - 1] : 0);
    cum[b * T_ + t] = c;
    if (t == T_ - 1) {
        total_out[b] = (float)c;   // total <= 15360, exact in fp32
    }
}

// --- Kernel 2: expand + tail-fill ----------------------------------------
// grid = (T_ + NFILL, B_), 192 threads. bi < T_: expand frame bi; else fill.
__global__ __launch_bounds__(NTHR) void lr_expand4(const float4* __restrict__ x,
                                                   const int* __restrict__ cum,
                                                   float4* __restrict__ out) {
    const int b  = blockIdx.y;
    const int bi = blockIdx.x;
    const int t  = threadIdx.x;
    const int* cb = cum + b * T_;

    if (bi < T_) {
        // ---- expand role: frame bi owns output rows [cum[bi-1], cum[bi]) --
        int end   = cb[bi];                       // wave-uniform scalar load
        int start = bi ? cb[bi - 1] : 0;          // wave-uniform scalar load
        if (end > ML_) end = ML_;                 // total may exceed MAXLEN
        if (start >= end) return;                 // dur==0 or fully clipped

        const int col = (t >= D4_) ? t - D4_ : t; // 0..95, lane's column
        const float4 v = x[((size_t)b * T_ + bi) * D4_ + col];
        float4* ob = out + (size_t)b * ML_ * D4_;

        // 2-row windows: t in [0,192) spans rows r (t<96) and r+1 (t>=96),
        // identical content -> each wave stores 1 KB contiguous per iter.
        int r = start;
        for (; r + 1 < end; r += 2)
            ob[(size_t)r * D4_ + t] = v;
        if (r < end && t < D4_)                   // odd-count tail row
            ob[(size_t)r * D4_ + t] = v;
    } else {
        // ---- fill role: zero rows [min(total,ML), ML), contiguous slices --
        const int fb    = bi - T_;                // 0..NFILL-1
        const int total = cb[T_ - 1];
        const int tr    = total < ML_ ? total : ML_;
        const int n     = (ML_ - tr) * D4_;       // float4 count to zero
        const int per   = (n + NFILL - 1) / NFILL;
        const int off   = fb * per;
        int cnt = n - off;
        if (cnt > per) cnt = per;
        if (cnt <= 0) return;
        float4* o = out + ((size_t)b * ML_ + tr) * D4_ + off;
        const float4 z = make_float4(0.f, 0.f, 0.f, 0.f);
        for (int j = t; j < cnt; j += NTHR)
            o[j] = z;
    }
}

extern "C" void kernel_launch(void* const* d_in, const int* in_sizes, int n_in,
                              void* d_out, int out_size, void* d_ws, size_t ws_size,
                              hipStream_t stream) {
    const float* x   = (const float*)d_in[0];   // (B, T, D) fp32
    const int*   dur = (const int*)d_in[1];     // (B, T) int32
    // d_in[2] = max_len scalar (always 8192 here)

    float* out       = (float*)d_out;                   // (B, ML, D) fp32
    float* total_out = out + (size_t)B_ * ML_ * D_;     // (B,) as fp32
    int*   cum       = (int*)d_ws;                      // (B, T) scratch

    lr_scan<<<B_, T_, 0, stream>>>(dur, cum, total_out);
    lr_expand4<<<dim3(T_ + NFILL, B_), NTHR, 0, stream>>>(
        (const float4*)x, cum, (float4*)out);
}